// Round 1
// baseline (290.926 us; speedup 1.0000x reference)
//
#include <hip/hip_runtime.h>

#define NB 4
#define CH 512
#define NN 4096
#define DD 64

typedef __attribute__((ext_vector_type(8))) short bf16x8;
typedef __attribute__((ext_vector_type(4))) float f32x4;

#define MFMA(a, b, c) __builtin_amdgcn_mfma_f32_16x16x32_bf16((a), (b), (c), 0, 0, 0)

__device__ inline unsigned short f2bf(float f) {
    unsigned int u = __builtin_bit_cast(unsigned int, f);
    unsigned int r = u + 0x7fffu + ((u >> 16) & 1u);
    return (unsigned short)(r >> 16);
}

__device__ inline bf16x8 ld8(const unsigned short* p) {
    return *reinterpret_cast<const bf16x8*>(p);
}

// ---------------- kernel 0: convert weights fp32 -> bf16 ----------------
__global__ __launch_bounds__(256) void convert_w(
    const float* __restrict__ Wq, const float* __restrict__ Wk,
    const float* __restrict__ Wv, const float* __restrict__ Wo,
    unsigned short* __restrict__ oq, unsigned short* __restrict__ ok,
    unsigned short* __restrict__ ov, unsigned short* __restrict__ oo) {
    int i = blockIdx.x * 256 + threadIdx.x;  // 32768 elems each
    oq[i] = f2bf(Wq[i]);
    ok[i] = f2bf(Wk[i]);
    ov[i] = f2bf(Wv[i]);
    oo[i] = f2bf(Wo[i]);
}

// ---------------- kernel 1: QKV projection ----------------
// Q (B,N,D) bf16, K (B,N,D) bf16, VT (B,D,N) bf16
__global__ __launch_bounds__(256) void qkv_kernel(
    const float* __restrict__ x,
    const unsigned short* __restrict__ Wq, const unsigned short* __restrict__ Wk,
    const unsigned short* __restrict__ Wv,
    const float* __restrict__ bq, const float* __restrict__ bk, const float* __restrict__ bv,
    unsigned short* __restrict__ Q, unsigned short* __restrict__ K,
    unsigned short* __restrict__ VT) {
    const int b = blockIdx.x >> 6;
    const int n0 = (blockIdx.x & 63) * 64;
    const int t = threadIdx.x;
    const int lane = t & 63, w = t >> 6;
    const int l15 = lane & 15, g = lane >> 4;

    __shared__ unsigned short sxT[64][72];  // [n][c], pad to 144B rows

    f32x4 accQ[4], accK[4], accV[4];
    const f32x4 z = {0.f, 0.f, 0.f, 0.f};
#pragma unroll
    for (int i = 0; i < 4; ++i) { accQ[i] = z; accK[i] = z; accV[i] = z; }

    for (int c0 = 0; c0 < CH; c0 += 64) {
        __syncthreads();  // protect prior-iter reads
        // stage x-tile transposed: sxT[n][c] = x[b][c0+c][n0+n], converted to bf16
#pragma unroll
        for (int p = 0; p < 16; ++p) {
            int nn = t & 63;
            int cc = (t >> 6) * 16 + p;
            float xv = x[((b * CH + c0 + cc) * NN) + n0 + nn];
            sxT[nn][cc] = f2bf(xv);
        }
        __syncthreads();
#pragma unroll
        for (int kk = 0; kk < 2; ++kk) {
            // x fragment: A for Q/K (row=n, k=c), B for VT (k=c, col=n)
            bf16x8 ax = ld8(&sxT[16 * w + l15][kk * 32 + 8 * g]);
            int c = c0 + kk * 32 + 8 * g;
#pragma unroll
            for (int dt = 0; dt < 4; ++dt) {
                int d = dt * 16 + l15;
                bf16x8 wq = ld8(&Wq[d * CH + c]);
                accQ[dt] = MFMA(ax, wq, accQ[dt]);
                bf16x8 wk = ld8(&Wk[d * CH + c]);
                accK[dt] = MFMA(ax, wk, accK[dt]);
                bf16x8 wv = ld8(&Wv[d * CH + c]);  // A-frag: row=d (tile dt), k=c
                accV[dt] = MFMA(wv, ax, accV[dt]);
            }
        }
    }

    // epilogue: Q/K rows n = n0+16w+4g+r, col d = 16dt+l15
#pragma unroll
    for (int dt = 0; dt < 4; ++dt) {
        int d = dt * 16 + l15;
        float biasq = bq[d], biask = bk[d];
#pragma unroll
        for (int r = 0; r < 4; ++r) {
            int n = n0 + 16 * w + 4 * g + r;
            Q[(b * NN + n) * DD + d] = f2bf(accQ[dt][r] + biasq);
            K[(b * NN + n) * DD + d] = f2bf(accK[dt][r] + biask);
        }
    }
    // VT rows d = 16dt+4g+r, col n = n0+16w+l15
#pragma unroll
    for (int dt = 0; dt < 4; ++dt) {
#pragma unroll
        for (int r = 0; r < 4; ++r) {
            int d = dt * 16 + 4 * g + r;
            VT[(b * DD + d) * NN + n0 + 16 * w + l15] = f2bf(accV[dt][r] + bv[d]);
        }
    }
}

// ---------------- kernel 2: flash attention ----------------
// ATT (B,N,D) bf16 = softmax(Q K^T) V
__global__ __launch_bounds__(256) void attn_kernel(
    const unsigned short* __restrict__ Q, const unsigned short* __restrict__ K,
    const unsigned short* __restrict__ VT, unsigned short* __restrict__ ATT) {
    const int b = blockIdx.x >> 6;
    const int n0 = (blockIdx.x & 63) * 64;
    const int t = threadIdx.x;
    const int lane = t & 63, w = t >> 6;
    const int l15 = lane & 15, g = lane >> 4;

    __shared__ unsigned short sK[64][72];   // [m][d]
    __shared__ unsigned short sVT[64][72];  // [d][m]
    __shared__ unsigned short sP[4][16][72];  // per-wave [n][m]

    // Q fragments (row = n-local l15, k = d)
    const int qrow = n0 + 16 * w + l15;
    bf16x8 qf0 = ld8(&Q[(b * NN + qrow) * DD + 0 + 8 * g]);
    bf16x8 qf1 = ld8(&Q[(b * NN + qrow) * DD + 32 + 8 * g]);

    f32x4 oacc[4];
    const f32x4 z = {0.f, 0.f, 0.f, 0.f};
#pragma unroll
    for (int i = 0; i < 4; ++i) oacc[i] = z;
    float m_run[4], l_run[4];
#pragma unroll
    for (int r = 0; r < 4; ++r) { m_run[r] = -1e30f; l_run[r] = 0.f; }

    for (int m0 = 0; m0 < NN; m0 += 64) {
        // stage K tile and VT tile
        {
            int row = t >> 2, c16 = (t & 3) * 16;
            const unsigned short* kp = &K[(b * NN + m0 + row) * DD + c16];
            *reinterpret_cast<bf16x8*>(&sK[row][c16]) = ld8(kp);
            *reinterpret_cast<bf16x8*>(&sK[row][c16 + 8]) = ld8(kp + 8);
            const unsigned short* vp = &VT[(b * DD + row) * NN + m0 + c16];
            *reinterpret_cast<bf16x8*>(&sVT[row][c16]) = ld8(vp);
            *reinterpret_cast<bf16x8*>(&sVT[row][c16 + 8]) = ld8(vp + 8);
        }
        __syncthreads();

        // S = Q K^T : 16 (n) x 64 (m) per wave
        f32x4 s[4];
#pragma unroll
        for (int ct = 0; ct < 4; ++ct) s[ct] = z;
#pragma unroll
        for (int ct = 0; ct < 4; ++ct) {
            bf16x8 kf0 = ld8(&sK[ct * 16 + l15][0 + 8 * g]);
            s[ct] = MFMA(qf0, kf0, s[ct]);
            bf16x8 kf1 = ld8(&sK[ct * 16 + l15][32 + 8 * g]);
            s[ct] = MFMA(qf1, kf1, s[ct]);
        }

        // online softmax; lane holds rows 4g+r, cols l15+16ct
        float corr[4];
#pragma unroll
        for (int r = 0; r < 4; ++r) {
            float mx = fmaxf(fmaxf(s[0][r], s[1][r]), fmaxf(s[2][r], s[3][r]));
#pragma unroll
            for (int d_ = 8; d_ >= 1; d_ >>= 1) mx = fmaxf(mx, __shfl_xor(mx, d_, 64));
            float mnew = fmaxf(m_run[r], mx);
            float c_ = __expf(m_run[r] - mnew);
            float rs = 0.f;
#pragma unroll
            for (int ct = 0; ct < 4; ++ct) {
                float p = __expf(s[ct][r] - mnew);
                s[ct][r] = p;
                rs += p;
            }
#pragma unroll
            for (int d_ = 8; d_ >= 1; d_ >>= 1) rs += __shfl_xor(rs, d_, 64);
            l_run[r] = l_run[r] * c_ + rs;
            m_run[r] = mnew;
            corr[r] = c_;
        }
#pragma unroll
        for (int dt = 0; dt < 4; ++dt)
#pragma unroll
            for (int r = 0; r < 4; ++r) oacc[dt][r] *= corr[r];

        // P -> LDS (wave-private; in-wave DS ordering suffices, no barrier)
#pragma unroll
        for (int ct = 0; ct < 4; ++ct)
#pragma unroll
            for (int r = 0; r < 4; ++r)
                sP[w][4 * g + r][ct * 16 + l15] = f2bf(s[ct][r]);

        // O += P V
#pragma unroll
        for (int kk = 0; kk < 2; ++kk) {
            bf16x8 pf = ld8(&sP[w][l15][kk * 32 + 8 * g]);
#pragma unroll
            for (int dt = 0; dt < 4; ++dt) {
                bf16x8 vf = ld8(&sVT[dt * 16 + l15][kk * 32 + 8 * g]);
                oacc[dt] = MFMA(pf, vf, oacc[dt]);
            }
        }
        __syncthreads();
    }

    // epilogue: normalize and store ATT (N,D) bf16
#pragma unroll
    for (int r = 0; r < 4; ++r) {
        float inv = 1.f / l_run[r];
        int n = n0 + 16 * w + 4 * g + r;
#pragma unroll
        for (int dt = 0; dt < 4; ++dt)
            ATT[(b * NN + n) * DD + dt * 16 + l15] = f2bf(oacc[dt][r] * inv);
    }
}

// ---------------- kernel 3: output projection + residual ----------------
__global__ __launch_bounds__(256) void out_kernel(
    const unsigned short* __restrict__ Wo, const unsigned short* __restrict__ ATT,
    const float* __restrict__ bo, const float* __restrict__ gamma,
    const float* __restrict__ x, float* __restrict__ out) {
    const int bid = blockIdx.x;
    const int b = bid >> 7;
    const int rest = bid & 127;
    const int n0 = (rest >> 1) * 64;
    const int c0 = (rest & 1) * 256;
    const int t = threadIdx.x;
    const int lane = t & 63, w = t >> 6;
    const int l15 = lane & 15, g = lane >> 4;
    const int cw = c0 + w * 64;

    f32x4 acc[4][4];  // [ct][nt]
    const f32x4 z = {0.f, 0.f, 0.f, 0.f};
#pragma unroll
    for (int i = 0; i < 4; ++i)
#pragma unroll
        for (int j = 0; j < 4; ++j) acc[i][j] = z;

#pragma unroll
    for (int kk = 0; kk < 2; ++kk) {
        bf16x8 af[4], bfr[4];
#pragma unroll
        for (int ct = 0; ct < 4; ++ct)
            af[ct] = ld8(&Wo[(cw + ct * 16 + l15) * DD + kk * 32 + 8 * g]);
#pragma unroll
        for (int nt = 0; nt < 4; ++nt)
            bfr[nt] = ld8(&ATT[(b * NN + n0 + nt * 16 + l15) * DD + kk * 32 + 8 * g]);
#pragma unroll
        for (int ct = 0; ct < 4; ++ct)
#pragma unroll
            for (int nt = 0; nt < 4; ++nt) acc[ct][nt] = MFMA(af[ct], bfr[nt], acc[ct][nt]);
    }

    float gm = gamma[0];
#pragma unroll
    for (int ct = 0; ct < 4; ++ct) {
        int c = cw + ct * 16 + 4 * g;
#pragma unroll
        for (int r = 0; r < 4; ++r) {
            float bias = bo[c + r];
#pragma unroll
            for (int nt = 0; nt < 4; ++nt) {
                int n = n0 + nt * 16 + l15;
                int idx = (b * CH + c + r) * NN + n;
                out[idx] = gm * (acc[ct][nt][r] + bias) + x[idx];
            }
        }
    }
}

extern "C" void kernel_launch(void* const* d_in, const int* in_sizes, int n_in,
                              void* d_out, int out_size, void* d_ws, size_t ws_size,
                              hipStream_t stream) {
    const float* x = (const float*)d_in[0];
    const float* Wq = (const float*)d_in[1];
    const float* bq = (const float*)d_in[2];
    const float* Wk = (const float*)d_in[3];
    const float* bk = (const float*)d_in[4];
    const float* Wv = (const float*)d_in[5];
    const float* bv = (const float*)d_in[6];
    const float* Wo = (const float*)d_in[7];
    const float* bo = (const float*)d_in[8];
    const float* gamma = (const float*)d_in[9];
    float* out = (float*)d_out;

    char* ws = (char*)d_ws;
    unsigned short* Wq_bf = (unsigned short*)(ws + 0);
    unsigned short* Wk_bf = (unsigned short*)(ws + 65536);
    unsigned short* Wv_bf = (unsigned short*)(ws + 131072);
    unsigned short* Wo_bf = (unsigned short*)(ws + 196608);
    unsigned short* Qb = (unsigned short*)(ws + 262144);
    unsigned short* Kb = (unsigned short*)(ws + 262144 + 2097152);
    unsigned short* VTb = (unsigned short*)(ws + 262144 + 2 * 2097152);
    unsigned short* ATTb = (unsigned short*)(ws + 262144 + 3 * 2097152);

    hipLaunchKernelGGL(convert_w, dim3(128), dim3(256), 0, stream,
                       Wq, Wk, Wv, Wo, Wq_bf, Wk_bf, Wv_bf, Wo_bf);
    hipLaunchKernelGGL(qkv_kernel, dim3(256), dim3(256), 0, stream,
                       x, Wq_bf, Wk_bf, Wv_bf, bq, bk, bv, Qb, Kb, VTb);
    hipLaunchKernelGGL(attn_kernel, dim3(256), dim3(256), 0, stream,
                       Qb, Kb, VTb, ATTb);
    hipLaunchKernelGGL(out_kernel, dim3(512), dim3(256), 0, stream,
                       Wo_bf, ATTb, bo, gamma, x, out);
}

// Round 2
// 217.494 us; speedup vs baseline: 1.3376x; 1.3376x over previous
//
#include <hip/hip_runtime.h>

#define NB 4
#define CH 512
#define NN 4096
#define DD 64

typedef __attribute__((ext_vector_type(8))) short bf16x8;
typedef __attribute__((ext_vector_type(4))) float f32x4;

#define MFMA(a, b, c) __builtin_amdgcn_mfma_f32_16x16x32_bf16((a), (b), (c), 0, 0, 0)

__device__ inline unsigned short f2bf(float f) {
    unsigned int u = __builtin_bit_cast(unsigned int, f);
    unsigned int r = u + 0x7fffu + ((u >> 16) & 1u);
    return (unsigned short)(r >> 16);
}

__device__ inline float bf2f(unsigned short u) {
    return __builtin_bit_cast(float, ((unsigned int)u) << 16);
}

__device__ inline bf16x8 ld8(const unsigned short* p) {
    return *reinterpret_cast<const bf16x8*>(p);
}

// ---------------- kernel 0: convert weights fp32 -> bf16 ----------------
__global__ __launch_bounds__(256) void convert_w(
    const float* __restrict__ Wq, const float* __restrict__ Wk,
    const float* __restrict__ Wv, const float* __restrict__ Wo,
    unsigned short* __restrict__ oq, unsigned short* __restrict__ ok,
    unsigned short* __restrict__ ov, unsigned short* __restrict__ oo) {
    int i = blockIdx.x * 256 + threadIdx.x;  // 32768 elems each
    oq[i] = f2bf(Wq[i]);
    ok[i] = f2bf(Wk[i]);
    ov[i] = f2bf(Wv[i]);
    oo[i] = f2bf(Wo[i]);
}

// ---------------- kernel 1: QKV projection ----------------
// Q (B,N,D) bf16, K (B,N,D) bf16, VT (B,D,N) bf16
// T14 async-stage: prefetch next x-tile into regs, write to LDS next iter.
__global__ __launch_bounds__(256) void qkv_kernel(
    const float* __restrict__ x,
    const unsigned short* __restrict__ Wq, const unsigned short* __restrict__ Wk,
    const unsigned short* __restrict__ Wv,
    const float* __restrict__ bq, const float* __restrict__ bk, const float* __restrict__ bv,
    unsigned short* __restrict__ Q, unsigned short* __restrict__ K,
    unsigned short* __restrict__ VT) {
    const int b = blockIdx.x >> 6;
    const int n0 = (blockIdx.x & 63) * 64;
    const int t = threadIdx.x;
    const int lane = t & 63, w = t >> 6;
    const int l15 = lane & 15, g = lane >> 4;
    const int nn = t & 63, ccb = (t >> 6) * 16;

    __shared__ unsigned short sxT[64][72];  // [n][c], pad to 144B rows

    f32x4 accQ[4], accK[4], accV[4];
    const f32x4 z = {0.f, 0.f, 0.f, 0.f};
#pragma unroll
    for (int i = 0; i < 4; ++i) { accQ[i] = z; accK[i] = z; accV[i] = z; }

    float rv[16];
#pragma unroll
    for (int p = 0; p < 16; ++p)
        rv[p] = x[((b * CH + ccb + p) * NN) + n0 + nn];

    for (int c0 = 0; c0 < CH; c0 += 64) {
        __syncthreads();  // protect prior-iter reads
#pragma unroll
        for (int p = 0; p < 16; ++p)
            sxT[nn][ccb + p] = f2bf(rv[p]);
        __syncthreads();
        if (c0 + 64 < CH) {
#pragma unroll
            for (int p = 0; p < 16; ++p)
                rv[p] = x[((b * CH + c0 + 64 + ccb + p) * NN) + n0 + nn];
        }
#pragma unroll
        for (int kk = 0; kk < 2; ++kk) {
            // x fragment: A for Q/K (row=n, k=c), B for VT (k=c, col=n)
            bf16x8 ax = ld8(&sxT[16 * w + l15][kk * 32 + 8 * g]);
            int c = c0 + kk * 32 + 8 * g;
#pragma unroll
            for (int dt = 0; dt < 4; ++dt) {
                int d = dt * 16 + l15;
                bf16x8 wq = ld8(&Wq[d * CH + c]);
                accQ[dt] = MFMA(ax, wq, accQ[dt]);
                bf16x8 wk = ld8(&Wk[d * CH + c]);
                accK[dt] = MFMA(ax, wk, accK[dt]);
                bf16x8 wv = ld8(&Wv[d * CH + c]);  // A-frag: row=d (tile dt), k=c
                accV[dt] = MFMA(wv, ax, accV[dt]);
            }
        }
    }

    // epilogue: Q/K rows n = n0+16w+4g+r, col d = 16dt+l15
#pragma unroll
    for (int dt = 0; dt < 4; ++dt) {
        int d = dt * 16 + l15;
        float biasq = bq[d], biask = bk[d];
#pragma unroll
        for (int r = 0; r < 4; ++r) {
            int n = n0 + 16 * w + 4 * g + r;
            Q[(b * NN + n) * DD + d] = f2bf(accQ[dt][r] + biasq);
            K[(b * NN + n) * DD + d] = f2bf(accK[dt][r] + biask);
        }
    }
    // VT rows d = 16dt+4g+r, col n = n0+16w+l15
#pragma unroll
    for (int dt = 0; dt < 4; ++dt) {
#pragma unroll
        for (int r = 0; r < 4; ++r) {
            int d = dt * 16 + 4 * g + r;
            VT[(b * DD + d) * NN + n0 + 16 * w + l15] = f2bf(accV[dt][r] + bv[d]);
        }
    }
}

// ---------------- kernel 2: flash attention, KV-split ----------------
// Each block: 64 q-rows x KVLEN kv-cols. Writes unnormalized O partial (bf16)
// and (m,l) (fp32) per row per split.
__global__ __launch_bounds__(256) void attn_kernel(
    const unsigned short* __restrict__ Q, const unsigned short* __restrict__ K,
    const unsigned short* __restrict__ VT,
    unsigned short* __restrict__ PO, float* __restrict__ PML, int KVLEN) {
    const int s = blockIdx.x >> 8;
    const int bq_ = blockIdx.x & 255;
    const int b = bq_ >> 6;
    const int n0 = (bq_ & 63) * 64;
    const int t = threadIdx.x;
    const int lane = t & 63, w = t >> 6;
    const int l15 = lane & 15, g = lane >> 4;

    __shared__ unsigned short sK[64][72];    // [m][d]
    __shared__ unsigned short sVT[64][72];   // [d][m]
    __shared__ unsigned short sP[4][16][72]; // per-wave [n][m]

    // Q fragments (row = n-local l15, k = d)
    const int qrow = n0 + 16 * w + l15;
    bf16x8 qf0 = ld8(&Q[(b * NN + qrow) * DD + 0 + 8 * g]);
    bf16x8 qf1 = ld8(&Q[(b * NN + qrow) * DD + 32 + 8 * g]);

    f32x4 oacc[4];
    const f32x4 z = {0.f, 0.f, 0.f, 0.f};
#pragma unroll
    for (int i = 0; i < 4; ++i) oacc[i] = z;
    float m_run[4], l_run[4];
#pragma unroll
    for (int r = 0; r < 4; ++r) { m_run[r] = -1e30f; l_run[r] = 0.f; }

    const int kv_begin = s * KVLEN;
    const int kv_end = kv_begin + KVLEN;
    for (int m0 = kv_begin; m0 < kv_end; m0 += 64) {
        // stage K tile and VT tile
        {
            int row = t >> 2, c16 = (t & 3) * 16;
            const unsigned short* kp = &K[(b * NN + m0 + row) * DD + c16];
            *reinterpret_cast<bf16x8*>(&sK[row][c16]) = ld8(kp);
            *reinterpret_cast<bf16x8*>(&sK[row][c16 + 8]) = ld8(kp + 8);
            const unsigned short* vp = &VT[(b * DD + row) * NN + m0 + c16];
            *reinterpret_cast<bf16x8*>(&sVT[row][c16]) = ld8(vp);
            *reinterpret_cast<bf16x8*>(&sVT[row][c16 + 8]) = ld8(vp + 8);
        }
        __syncthreads();

        // S = Q K^T : 16 (n) x 64 (m) per wave
        f32x4 sv[4];
#pragma unroll
        for (int ct = 0; ct < 4; ++ct) sv[ct] = z;
#pragma unroll
        for (int ct = 0; ct < 4; ++ct) {
            bf16x8 kf0 = ld8(&sK[ct * 16 + l15][0 + 8 * g]);
            sv[ct] = MFMA(qf0, kf0, sv[ct]);
            bf16x8 kf1 = ld8(&sK[ct * 16 + l15][32 + 8 * g]);
            sv[ct] = MFMA(qf1, kf1, sv[ct]);
        }

        // online softmax; lane holds rows 4g+r, cols l15+16ct
        float corr[4];
#pragma unroll
        for (int r = 0; r < 4; ++r) {
            float mx = fmaxf(fmaxf(sv[0][r], sv[1][r]), fmaxf(sv[2][r], sv[3][r]));
#pragma unroll
            for (int d_ = 8; d_ >= 1; d_ >>= 1) mx = fmaxf(mx, __shfl_xor(mx, d_, 64));
            float mnew = fmaxf(m_run[r], mx);
            float c_ = __expf(m_run[r] - mnew);
            float rs = 0.f;
#pragma unroll
            for (int ct = 0; ct < 4; ++ct) {
                float p = __expf(sv[ct][r] - mnew);
                sv[ct][r] = p;
                rs += p;
            }
#pragma unroll
            for (int d_ = 8; d_ >= 1; d_ >>= 1) rs += __shfl_xor(rs, d_, 64);
            l_run[r] = l_run[r] * c_ + rs;
            m_run[r] = mnew;
            corr[r] = c_;
        }
#pragma unroll
        for (int dt = 0; dt < 4; ++dt)
#pragma unroll
            for (int r = 0; r < 4; ++r) oacc[dt][r] *= corr[r];

        // P -> LDS (wave-private; in-wave DS ordering suffices, no barrier)
#pragma unroll
        for (int ct = 0; ct < 4; ++ct)
#pragma unroll
            for (int r = 0; r < 4; ++r)
                sP[w][4 * g + r][ct * 16 + l15] = f2bf(sv[ct][r]);

        // O += P V
#pragma unroll
        for (int kk = 0; kk < 2; ++kk) {
            bf16x8 pf = ld8(&sP[w][l15][kk * 32 + 8 * g]);
#pragma unroll
            for (int dt = 0; dt < 4; ++dt) {
                bf16x8 vf = ld8(&sVT[dt * 16 + l15][kk * 32 + 8 * g]);
                oacc[dt] = MFMA(pf, vf, oacc[dt]);
            }
        }
        __syncthreads();
    }

    // epilogue: store unnormalized partial O + (m,l)
#pragma unroll
    for (int r = 0; r < 4; ++r) {
        int n = n0 + 16 * w + 4 * g + r;
        size_t rowidx = (size_t)s * NB * NN + (size_t)b * NN + n;
#pragma unroll
        for (int dt = 0; dt < 4; ++dt)
            PO[rowidx * DD + dt * 16 + l15] = f2bf(oacc[dt][r]);
        if (l15 == 0) {
            PML[rowidx * 2 + 0] = m_run[r];
            PML[rowidx * 2 + 1] = l_run[r];
        }
    }
}

// ---------------- kernel 2b: combine KV-split partials ----------------
__global__ __launch_bounds__(256) void attn_combine(
    const unsigned short* __restrict__ PO, const float* __restrict__ PML,
    unsigned short* __restrict__ ATT, int S) {
    const int t = threadIdx.x;
    const int R = blockIdx.x * 64 + (t >> 2);  // global row in [0, B*N)
    const int dq = (t & 3) * 16;

    float m = -1e30f;
    for (int s = 0; s < S; ++s) m = fmaxf(m, PML[((size_t)s * NB * NN + R) * 2]);

    float acc[16];
#pragma unroll
    for (int j = 0; j < 16; ++j) acc[j] = 0.f;
    float l = 0.f;
    for (int s = 0; s < S; ++s) {
        size_t rowidx = (size_t)s * NB * NN + R;
        float ms = PML[rowidx * 2 + 0];
        float ls = PML[rowidx * 2 + 1];
        float wgt = __expf(ms - m);
        l += wgt * ls;
        bf16x8 a0 = ld8(&PO[rowidx * DD + dq]);
        bf16x8 a1 = ld8(&PO[rowidx * DD + dq + 8]);
#pragma unroll
        for (int j = 0; j < 8; ++j) {
            acc[j] += wgt * bf2f((unsigned short)a0[j]);
            acc[8 + j] += wgt * bf2f((unsigned short)a1[j]);
        }
    }
    float inv = 1.f / l;
    bf16x8 o0, o1;
#pragma unroll
    for (int j = 0; j < 8; ++j) {
        o0[j] = (short)f2bf(acc[j] * inv);
        o1[j] = (short)f2bf(acc[8 + j] * inv);
    }
    *reinterpret_cast<bf16x8*>(&ATT[(size_t)R * DD + dq]) = o0;
    *reinterpret_cast<bf16x8*>(&ATT[(size_t)R * DD + dq + 8]) = o1;
}

// ---------------- kernel 3: output projection + residual ----------------
// grid: b(2) | n-tile(6) | c-tile(2); block 256; wave w: 32 c x 64 n
__global__ __launch_bounds__(256) void out_kernel(
    const unsigned short* __restrict__ Wo, const unsigned short* __restrict__ ATT,
    const float* __restrict__ bo, const float* __restrict__ gamma,
    const float* __restrict__ x, float* __restrict__ out) {
    const int bid = blockIdx.x;
    const int b = bid >> 8;
    const int rest = bid & 255;
    const int n0 = (rest >> 2) * 64;
    const int c0 = (rest & 3) * 128;
    const int t = threadIdx.x;
    const int lane = t & 63, w = t >> 6;
    const int l15 = lane & 15, g = lane >> 4;
    const int cw = c0 + w * 32;

    f32x4 acc[2][4];  // [ct][nt]
    const f32x4 z = {0.f, 0.f, 0.f, 0.f};
#pragma unroll
    for (int i = 0; i < 2; ++i)
#pragma unroll
        for (int j = 0; j < 4; ++j) acc[i][j] = z;

#pragma unroll
    for (int kk = 0; kk < 2; ++kk) {
        bf16x8 af[2], bfr[4];
#pragma unroll
        for (int ct = 0; ct < 2; ++ct)
            af[ct] = ld8(&Wo[(cw + ct * 16 + l15) * DD + kk * 32 + 8 * g]);
#pragma unroll
        for (int nt = 0; nt < 4; ++nt)
            bfr[nt] = ld8(&ATT[((size_t)b * NN + n0 + nt * 16 + l15) * DD + kk * 32 + 8 * g]);
#pragma unroll
        for (int ct = 0; ct < 2; ++ct)
#pragma unroll
            for (int nt = 0; nt < 4; ++nt) acc[ct][nt] = MFMA(af[ct], bfr[nt], acc[ct][nt]);
    }

    float gm = gamma[0];
#pragma unroll
    for (int ct = 0; ct < 2; ++ct) {
        int c = cw + ct * 16 + 4 * g;
#pragma unroll
        for (int r = 0; r < 4; ++r) {
            float bias = bo[c + r];
#pragma unroll
            for (int nt = 0; nt < 4; ++nt) {
                int n = n0 + nt * 16 + l15;
                int idx = (b * CH + c + r) * NN + n;
                out[idx] = gm * (acc[ct][nt][r] + bias) + x[idx];
            }
        }
    }
}

extern "C" void kernel_launch(void* const* d_in, const int* in_sizes, int n_in,
                              void* d_out, int out_size, void* d_ws, size_t ws_size,
                              hipStream_t stream) {
    const float* x = (const float*)d_in[0];
    const float* Wq = (const float*)d_in[1];
    const float* bq = (const float*)d_in[2];
    const float* Wk = (const float*)d_in[3];
    const float* bk = (const float*)d_in[4];
    const float* Wv = (const float*)d_in[5];
    const float* bv = (const float*)d_in[6];
    const float* Wo = (const float*)d_in[7];
    const float* bo = (const float*)d_in[8];
    const float* gamma = (const float*)d_in[9];
    float* out = (float*)d_out;

    char* ws = (char*)d_ws;
    unsigned short* Wq_bf = (unsigned short*)(ws + 0);
    unsigned short* Wk_bf = (unsigned short*)(ws + 65536);
    unsigned short* Wv_bf = (unsigned short*)(ws + 131072);
    unsigned short* Wo_bf = (unsigned short*)(ws + 196608);
    unsigned short* Qb = (unsigned short*)(ws + 262144);
    unsigned short* Kb = (unsigned short*)(ws + 262144 + 2097152);
    unsigned short* VTb = (unsigned short*)(ws + 262144 + 2 * 2097152);
    unsigned short* ATTb = (unsigned short*)(ws + 262144 + 3 * 2097152);
    size_t po_off = 262144 + 4 * 2097152;

    // KV-split factor: 4 if workspace allows, else 1 (deterministic per session)
    size_t need4 = po_off + 4ull * ((size_t)NB * NN * DD * 2 + (size_t)NB * NN * 8);
    int S = (ws_size >= need4) ? 4 : 1;
    unsigned short* PO = (unsigned short*)(ws + po_off);
    float* PML = (float*)(ws + po_off + (size_t)S * NB * NN * DD * 2);

    hipLaunchKernelGGL(convert_w, dim3(128), dim3(256), 0, stream,
                       Wq, Wk, Wv, Wo, Wq_bf, Wk_bf, Wv_bf, Wo_bf);
    hipLaunchKernelGGL(qkv_kernel, dim3(256), dim3(256), 0, stream,
                       x, Wq_bf, Wk_bf, Wv_bf, bq, bk, bv, Qb, Kb, VTb);
    hipLaunchKernelGGL(attn_kernel, dim3(256 * S), dim3(256), 0, stream,
                       Qb, Kb, VTb, PO, PML, NN / S);
    hipLaunchKernelGGL(attn_combine, dim3(NB * NN / 64), dim3(256), 0, stream,
                       PO, PML, ATTb, S);
    hipLaunchKernelGGL(out_kernel, dim3(1024), dim3(256), 0, stream,
                       Wo_bf, ATTb, bo, gamma, x, out);
}

// Round 3
// 214.399 us; speedup vs baseline: 1.3569x; 1.0144x over previous
//
#include <hip/hip_runtime.h>

#define NB 4
#define CH 512
#define NN 4096
#define DD 64

typedef __attribute__((ext_vector_type(8))) short bf16x8;
typedef __attribute__((ext_vector_type(4))) float f32x4;

#define MFMA(a, b, c) __builtin_amdgcn_mfma_f32_16x16x32_bf16((a), (b), (c), 0, 0, 0)

__device__ inline unsigned short f2bf(float f) {
    unsigned int u = __builtin_bit_cast(unsigned int, f);
    unsigned int r = u + 0x7fffu + ((u >> 16) & 1u);
    return (unsigned short)(r >> 16);
}

__device__ inline float bf2f(unsigned short u) {
    return __builtin_bit_cast(float, ((unsigned int)u) << 16);
}

__device__ inline bf16x8 ld8(const unsigned short* p) {
    return *reinterpret_cast<const bf16x8*>(p);
}

// ---------------- kernel 0: convert weights fp32 -> bf16 ----------------
__global__ __launch_bounds__(256) void convert_w(
    const float* __restrict__ Wq, const float* __restrict__ Wk,
    const float* __restrict__ Wv, const float* __restrict__ Wo,
    unsigned short* __restrict__ oq, unsigned short* __restrict__ ok,
    unsigned short* __restrict__ ov, unsigned short* __restrict__ oo) {
    int i = blockIdx.x * 256 + threadIdx.x;  // 32768 elems each
    oq[i] = f2bf(Wq[i]);
    ok[i] = f2bf(Wk[i]);
    ov[i] = f2bf(Wv[i]);
    oo[i] = f2bf(Wo[i]);
}

// ---------------- kernel 1: QKV projection ----------------
// grid B*256: n-tile of 16 rows per block; 4 waves split C into 128-ch chunks,
// cross-wave f32 reduction in LDS; wave 0 stores Q,K (N,D) and VT (D,N).
__global__ __launch_bounds__(256) void qkv_kernel(
    const float* __restrict__ x,
    const unsigned short* __restrict__ Wq, const unsigned short* __restrict__ Wk,
    const unsigned short* __restrict__ Wv,
    const float* __restrict__ bq, const float* __restrict__ bk, const float* __restrict__ bv,
    unsigned short* __restrict__ Q, unsigned short* __restrict__ K,
    unsigned short* __restrict__ VT) {
    const int b = blockIdx.x >> 8;
    const int n0 = (blockIdx.x & 255) * 16;
    const int t = threadIdx.x;
    const int lane = t & 63, w = t >> 6;
    const int l15 = lane & 15, g = lane >> 4;

    __shared__ char smraw[36864];  // max(sxT 16*520*2, red 3*64*48*4)
    unsigned short (*sxT)[520] = (unsigned short(*)[520])smraw;  // [n][c]
    float* red = (float*)smraw;

    // stage full x-tile transposed: sxT[n][c] = x[b][c][n0+n]
    {
        const int cbase = t >> 2;
        const int nq = (t & 3) * 4;
#pragma unroll
        for (int p = 0; p < 8; ++p) {
            int c = p * 64 + cbase;
            float4 v = *reinterpret_cast<const float4*>(
                &x[((size_t)(b * CH + c)) * NN + n0 + nq]);
            sxT[nq + 0][c] = f2bf(v.x);
            sxT[nq + 1][c] = f2bf(v.y);
            sxT[nq + 2][c] = f2bf(v.z);
            sxT[nq + 3][c] = f2bf(v.w);
        }
    }
    __syncthreads();

    f32x4 accQ[4], accK[4], accV[4];
    const f32x4 z = {0.f, 0.f, 0.f, 0.f};
#pragma unroll
    for (int i = 0; i < 4; ++i) { accQ[i] = z; accK[i] = z; accV[i] = z; }

    const int wc = w * 128;
#pragma unroll
    for (int i = 0; i < 4; ++i) {
        int c = wc + i * 32 + 8 * g;
        bf16x8 ax = ld8(&sxT[l15][c]);
#pragma unroll
        for (int dt = 0; dt < 4; ++dt) {
            int d = dt * 16 + l15;
            accQ[dt] = MFMA(ax, ld8(&Wq[d * CH + c]), accQ[dt]);
            accK[dt] = MFMA(ax, ld8(&Wk[d * CH + c]), accK[dt]);
            accV[dt] = MFMA(ld8(&Wv[d * CH + c]), ax, accV[dt]);
        }
    }
    __syncthreads();  // done reading sxT; region becomes red

    if (w > 0) {
        float* dst = &red[((w - 1) * 64 + lane) * 48];
#pragma unroll
        for (int i = 0; i < 4; ++i) {
            *reinterpret_cast<f32x4*>(&dst[i * 4]) = accQ[i];
            *reinterpret_cast<f32x4*>(&dst[16 + i * 4]) = accK[i];
            *reinterpret_cast<f32x4*>(&dst[32 + i * 4]) = accV[i];
        }
    }
    __syncthreads();
    if (w == 0) {
#pragma unroll
        for (int ww = 0; ww < 3; ++ww) {
            const float* src = &red[(ww * 64 + lane) * 48];
#pragma unroll
            for (int i = 0; i < 4; ++i) {
                accQ[i] += *reinterpret_cast<const f32x4*>(&src[i * 4]);
                accK[i] += *reinterpret_cast<const f32x4*>(&src[16 + i * 4]);
                accV[i] += *reinterpret_cast<const f32x4*>(&src[32 + i * 4]);
            }
        }
        // Q/K: row n = n0+4g+r, col d = 16dt+l15
#pragma unroll
        for (int dt = 0; dt < 4; ++dt) {
            int d = dt * 16 + l15;
            float biasq = bq[d], biask = bk[d];
#pragma unroll
            for (int r = 0; r < 4; ++r) {
                int n = n0 + 4 * g + r;
                Q[((size_t)b * NN + n) * DD + d] = f2bf(accQ[dt][r] + biasq);
                K[((size_t)b * NN + n) * DD + d] = f2bf(accK[dt][r] + biask);
            }
        }
        // VT: row d = 16dt+4g+r, col n = n0+l15
#pragma unroll
        for (int dt = 0; dt < 4; ++dt) {
#pragma unroll
            for (int r = 0; r < 4; ++r) {
                int d = dt * 16 + 4 * g + r;
                VT[((size_t)b * DD + d) * NN + n0 + l15] = f2bf(accV[dt][r] + bv[d]);
            }
        }
    }
}

// ---------------- kernel 2: flash attention, KV-split ----------------
__global__ __launch_bounds__(256) void attn_kernel(
    const unsigned short* __restrict__ Q, const unsigned short* __restrict__ K,
    const unsigned short* __restrict__ VT,
    unsigned short* __restrict__ PO, float* __restrict__ PML, int KVLEN) {
    const int s = blockIdx.x >> 8;
    const int bq_ = blockIdx.x & 255;
    const int b = bq_ >> 6;
    const int n0 = (bq_ & 63) * 64;
    const int t = threadIdx.x;
    const int lane = t & 63, w = t >> 6;
    const int l15 = lane & 15, g = lane >> 4;

    __shared__ unsigned short sK[64][72];    // [m][d]
    __shared__ unsigned short sVT[64][72];   // [d][m]
    __shared__ unsigned short sP[4][16][76]; // per-wave [n][m]; stride 76 spreads g-groups

    const int qrow = n0 + 16 * w + l15;
    bf16x8 qf0 = ld8(&Q[((size_t)b * NN + qrow) * DD + 0 + 8 * g]);
    bf16x8 qf1 = ld8(&Q[((size_t)b * NN + qrow) * DD + 32 + 8 * g]);

    f32x4 oacc[4];
    const f32x4 z = {0.f, 0.f, 0.f, 0.f};
#pragma unroll
    for (int i = 0; i < 4; ++i) oacc[i] = z;
    float m_run[4], l_run[4];
#pragma unroll
    for (int r = 0; r < 4; ++r) { m_run[r] = -1e30f; l_run[r] = 0.f; }

    const int kv_begin = s * KVLEN;
    const int kv_end = kv_begin + KVLEN;
    for (int m0 = kv_begin; m0 < kv_end; m0 += 64) {
        {
            int row = t >> 2, c16 = (t & 3) * 16;
            const unsigned short* kp = &K[((size_t)b * NN + m0 + row) * DD + c16];
            *reinterpret_cast<bf16x8*>(&sK[row][c16]) = ld8(kp);
            *reinterpret_cast<bf16x8*>(&sK[row][c16 + 8]) = ld8(kp + 8);
            const unsigned short* vp = &VT[((size_t)b * DD + row) * NN + m0 + c16];
            *reinterpret_cast<bf16x8*>(&sVT[row][c16]) = ld8(vp);
            *reinterpret_cast<bf16x8*>(&sVT[row][c16 + 8]) = ld8(vp + 8);
        }
        __syncthreads();

        f32x4 sv[4];
#pragma unroll
        for (int ct = 0; ct < 4; ++ct) sv[ct] = z;
#pragma unroll
        for (int ct = 0; ct < 4; ++ct) {
            bf16x8 kf0 = ld8(&sK[ct * 16 + l15][0 + 8 * g]);
            sv[ct] = MFMA(qf0, kf0, sv[ct]);
            bf16x8 kf1 = ld8(&sK[ct * 16 + l15][32 + 8 * g]);
            sv[ct] = MFMA(qf1, kf1, sv[ct]);
        }

        float corr[4];
#pragma unroll
        for (int r = 0; r < 4; ++r) {
            float mx = fmaxf(fmaxf(sv[0][r], sv[1][r]), fmaxf(sv[2][r], sv[3][r]));
#pragma unroll
            for (int d_ = 8; d_ >= 1; d_ >>= 1) mx = fmaxf(mx, __shfl_xor(mx, d_, 64));
            float mnew = fmaxf(m_run[r], mx);
            float c_ = __expf(m_run[r] - mnew);
            float rs = 0.f;
#pragma unroll
            for (int ct = 0; ct < 4; ++ct) {
                float p = __expf(sv[ct][r] - mnew);
                sv[ct][r] = p;
                rs += p;
            }
#pragma unroll
            for (int d_ = 8; d_ >= 1; d_ >>= 1) rs += __shfl_xor(rs, d_, 64);
            l_run[r] = l_run[r] * c_ + rs;
            m_run[r] = mnew;
            corr[r] = c_;
        }
#pragma unroll
        for (int dt = 0; dt < 4; ++dt)
#pragma unroll
            for (int r = 0; r < 4; ++r) oacc[dt][r] *= corr[r];

#pragma unroll
        for (int ct = 0; ct < 4; ++ct)
#pragma unroll
            for (int r = 0; r < 4; ++r)
                sP[w][4 * g + r][ct * 16 + l15] = f2bf(sv[ct][r]);

#pragma unroll
        for (int kk = 0; kk < 2; ++kk) {
            bf16x8 pf = ld8(&sP[w][l15][kk * 32 + 8 * g]);
#pragma unroll
            for (int dt = 0; dt < 4; ++dt) {
                bf16x8 vf = ld8(&sVT[dt * 16 + l15][kk * 32 + 8 * g]);
                oacc[dt] = MFMA(pf, vf, oacc[dt]);
            }
        }
        __syncthreads();
    }

#pragma unroll
    for (int r = 0; r < 4; ++r) {
        int n = n0 + 16 * w + 4 * g + r;
        size_t rowidx = (size_t)s * NB * NN + (size_t)b * NN + n;
#pragma unroll
        for (int dt = 0; dt < 4; ++dt)
            PO[rowidx * DD + dt * 16 + l15] = f2bf(oacc[dt][r]);
        if (l15 == 0) {
            PML[rowidx * 2 + 0] = m_run[r];
            PML[rowidx * 2 + 1] = l_run[r];
        }
    }
}

// ---------------- kernel 3: combine + output projection + residual ----------------
// grid 1024: b | n-tile(64 rows) | c-tile(128). Phase 1: combine partials into
// LDS sATT[64][72]; Phase 2: MFMA vs Wo; epilogue gamma*(.)+x.
__global__ __launch_bounds__(256) void out_fused(
    const unsigned short* __restrict__ Wo, const unsigned short* __restrict__ PO,
    const float* __restrict__ PML, const float* __restrict__ bo,
    const float* __restrict__ gamma, const float* __restrict__ x,
    float* __restrict__ out, int S) {
    const int bid = blockIdx.x;
    const int b = bid >> 8;
    const int rest = bid & 255;
    const int n0 = (rest >> 2) * 64;
    const int c0 = (rest & 3) * 128;
    const int t = threadIdx.x;
    const int lane = t & 63, w = t >> 6;
    const int l15 = lane & 15, g = lane >> 4;

    __shared__ unsigned short sATT[64][72];  // [n][d]

    // phase 1: combine KV-split partials for this n-tile
    {
        const int row = t >> 2;
        const int dq = (t & 3) * 16;
        const size_t base = (size_t)b * NN + n0 + row;
        float m = -1e30f;
        for (int s = 0; s < S; ++s)
            m = fmaxf(m, PML[((size_t)s * NB * NN + base) * 2]);
        float acc[16];
#pragma unroll
        for (int j = 0; j < 16; ++j) acc[j] = 0.f;
        float l = 0.f;
        for (int s = 0; s < S; ++s) {
            size_t rowidx = (size_t)s * NB * NN + base;
            float ms = PML[rowidx * 2 + 0];
            float ls = PML[rowidx * 2 + 1];
            float wgt = __expf(ms - m);
            l += wgt * ls;
            bf16x8 a0 = ld8(&PO[rowidx * DD + dq]);
            bf16x8 a1 = ld8(&PO[rowidx * DD + dq + 8]);
#pragma unroll
            for (int j = 0; j < 8; ++j) {
                acc[j] += wgt * bf2f((unsigned short)a0[j]);
                acc[8 + j] += wgt * bf2f((unsigned short)a1[j]);
            }
        }
        float inv = 1.f / l;
        bf16x8 o0, o1;
#pragma unroll
        for (int j = 0; j < 8; ++j) {
            o0[j] = (short)f2bf(acc[j] * inv);
            o1[j] = (short)f2bf(acc[8 + j] * inv);
        }
        *reinterpret_cast<bf16x8*>(&sATT[row][dq]) = o0;
        *reinterpret_cast<bf16x8*>(&sATT[row][dq + 8]) = o1;
    }
    __syncthreads();

    // phase 2: out[c, n] = gamma*(Wo . att + bo) + x
    const int cw = c0 + w * 32;
    f32x4 acc2[2][4];
    const f32x4 z = {0.f, 0.f, 0.f, 0.f};
#pragma unroll
    for (int i = 0; i < 2; ++i)
#pragma unroll
        for (int j = 0; j < 4; ++j) acc2[i][j] = z;

#pragma unroll
    for (int kk = 0; kk < 2; ++kk) {
        bf16x8 af[2], bfr[4];
#pragma unroll
        for (int ct = 0; ct < 2; ++ct)
            af[ct] = ld8(&Wo[(cw + ct * 16 + l15) * DD + kk * 32 + 8 * g]);
#pragma unroll
        for (int nt = 0; nt < 4; ++nt)
            bfr[nt] = ld8(&sATT[nt * 16 + l15][kk * 32 + 8 * g]);
#pragma unroll
        for (int ct = 0; ct < 2; ++ct)
#pragma unroll
            for (int nt = 0; nt < 4; ++nt) acc2[ct][nt] = MFMA(af[ct], bfr[nt], acc2[ct][nt]);
    }

    float gm = gamma[0];
#pragma unroll
    for (int ct = 0; ct < 2; ++ct) {
        int c = cw + ct * 16 + 4 * g;
#pragma unroll
        for (int r = 0; r < 4; ++r) {
            float bias = bo[c + r];
#pragma unroll
            for (int nt = 0; nt < 4; ++nt) {
                int n = n0 + nt * 16 + l15;
                size_t idx = ((size_t)b * CH + c + r) * NN + n;
                out[idx] = gm * (acc2[ct][nt][r] + bias) + x[idx];
            }
        }
    }
}

extern "C" void kernel_launch(void* const* d_in, const int* in_sizes, int n_in,
                              void* d_out, int out_size, void* d_ws, size_t ws_size,
                              hipStream_t stream) {
    const float* x = (const float*)d_in[0];
    const float* Wq = (const float*)d_in[1];
    const float* bq = (const float*)d_in[2];
    const float* Wk = (const float*)d_in[3];
    const float* bk = (const float*)d_in[4];
    const float* Wv = (const float*)d_in[5];
    const float* bv = (const float*)d_in[6];
    const float* Wo = (const float*)d_in[7];
    const float* bo = (const float*)d_in[8];
    const float* gamma = (const float*)d_in[9];
    float* out = (float*)d_out;

    char* ws = (char*)d_ws;
    unsigned short* Wq_bf = (unsigned short*)(ws + 0);
    unsigned short* Wk_bf = (unsigned short*)(ws + 65536);
    unsigned short* Wv_bf = (unsigned short*)(ws + 131072);
    unsigned short* Wo_bf = (unsigned short*)(ws + 196608);
    unsigned short* Qb = (unsigned short*)(ws + 262144);
    unsigned short* Kb = (unsigned short*)(ws + 262144 + 2097152);
    unsigned short* VTb = (unsigned short*)(ws + 262144 + 2 * 2097152);
    const size_t po_off = 262144 + 3ull * 2097152;

    // KV-split factor (deterministic per session: depends only on ws_size)
    int S = 8;
    while (S > 1 &&
           ws_size < po_off + (size_t)S * (2097152ull + 131072ull))
        S >>= 1;
    unsigned short* PO = (unsigned short*)(ws + po_off);
    float* PML = (float*)(ws + po_off + (size_t)S * 2097152ull);

    hipLaunchKernelGGL(convert_w, dim3(128), dim3(256), 0, stream,
                       Wq, Wk, Wv, Wo, Wq_bf, Wk_bf, Wv_bf, Wo_bf);
    hipLaunchKernelGGL(qkv_kernel, dim3(1024), dim3(256), 0, stream,
                       x, Wq_bf, Wk_bf, Wv_bf, bq, bk, bv, Qb, Kb, VTb);
    hipLaunchKernelGGL(attn_kernel, dim3(256 * S), dim3(256), 0, stream,
                       Qb, Kb, VTb, PO, PML, NN / S);
    hipLaunchKernelGGL(out_fused, dim3(1024), dim3(256), 0, stream,
                       Wo_bf, PO, PML, bo, gamma, x, out, S);
}

// Round 7
// 195.574 us; speedup vs baseline: 1.4875x; 1.0963x over previous
//
#include <hip/hip_runtime.h>

#define NB 4
#define CH 512
#define NN 4096
#define DD 64

typedef __attribute__((ext_vector_type(8))) short bf16x8;
typedef __attribute__((ext_vector_type(4))) float f32x4;

#define MFMA(a, b, c) __builtin_amdgcn_mfma_f32_16x16x32_bf16((a), (b), (c), 0, 0, 0)

__device__ inline unsigned short f2bf(float f) {
    unsigned int u = __builtin_bit_cast(unsigned int, f);
    unsigned int r = u + 0x7fffu + ((u >> 16) & 1u);
    return (unsigned short)(r >> 16);
}

__device__ inline unsigned short f2bf_trunc(float f) {
    return (unsigned short)(__builtin_bit_cast(unsigned int, f) >> 16);
}

__device__ inline float bf2f(unsigned short u) {
    return __builtin_bit_cast(float, ((unsigned int)u) << 16);
}

__device__ inline bf16x8 ld8(const unsigned short* p) {
    return *reinterpret_cast<const bf16x8*>(p);
}

// ---------------- kernel 0: convert weights fp32 -> bf16 ----------------
__global__ __launch_bounds__(256) void convert_w(
    const float* __restrict__ Wq, const float* __restrict__ Wk,
    const float* __restrict__ Wv, const float* __restrict__ Wo,
    unsigned short* __restrict__ oq, unsigned short* __restrict__ ok,
    unsigned short* __restrict__ ov, unsigned short* __restrict__ oo) {
    int i = blockIdx.x * 256 + threadIdx.x;  // 32768 elems each
    oq[i] = f2bf(Wq[i]);
    ok[i] = f2bf(Wk[i]);
    ov[i] = f2bf(Wv[i]);
    oo[i] = f2bf(Wo[i]);
}

// ---------------- kernel 1: QKV projection ----------------
// grid B*256: n-tile of 16 rows; 4 waves split C into 128-ch chunks;
// cross-wave reduction in LDS; epilogue distributed: wave w stores dt=w slice.
__global__ __launch_bounds__(256) void qkv_kernel(
    const float* __restrict__ x,
    const unsigned short* __restrict__ Wq, const unsigned short* __restrict__ Wk,
    const unsigned short* __restrict__ Wv,
    const float* __restrict__ bq, const float* __restrict__ bk, const float* __restrict__ bv,
    unsigned short* __restrict__ Q, unsigned short* __restrict__ K,
    unsigned short* __restrict__ VT) {
    const int b = blockIdx.x >> 8;
    const int n0 = (blockIdx.x & 255) * 16;
    const int t = threadIdx.x;
    const int lane = t & 63, w = t >> 6;
    const int l15 = lane & 15, g = lane >> 4;

    __shared__ char smraw[49152];  // max(sxT 16*520*2=16640, red 4*4*64*12*4=49152)
    unsigned short (*sxT)[520] = (unsigned short(*)[520])smraw;       // [n][c]
    float (*red)[4][64][12] = (float(*)[4][64][12])smraw;             // [dt][src][lane][12]

    // stage full x-tile transposed: sxT[n][c] = x[b][c][n0+n]
    {
        const int cbase = t >> 2;
        const int nq = (t & 3) * 4;
#pragma unroll
        for (int p = 0; p < 8; ++p) {
            int c = p * 64 + cbase;
            float4 v = *reinterpret_cast<const float4*>(
                &x[((size_t)(b * CH + c)) * NN + n0 + nq]);
            sxT[nq + 0][c] = f2bf(v.x);
            sxT[nq + 1][c] = f2bf(v.y);
            sxT[nq + 2][c] = f2bf(v.z);
            sxT[nq + 3][c] = f2bf(v.w);
        }
    }
    __syncthreads();

    f32x4 accQ[4], accK[4], accV[4];
    const f32x4 z = {0.f, 0.f, 0.f, 0.f};
#pragma unroll
    for (int i = 0; i < 4; ++i) { accQ[i] = z; accK[i] = z; accV[i] = z; }

    const int wc = w * 128;
#pragma unroll
    for (int i = 0; i < 4; ++i) {
        int c = wc + i * 32 + 8 * g;
        bf16x8 ax = ld8(&sxT[l15][c]);
#pragma unroll
        for (int dt = 0; dt < 4; ++dt) {
            int d = dt * 16 + l15;
            accQ[dt] = MFMA(ax, ld8(&Wq[d * CH + c]), accQ[dt]);
            accK[dt] = MFMA(ax, ld8(&Wk[d * CH + c]), accK[dt]);
            accV[dt] = MFMA(ld8(&Wv[d * CH + c]), ax, accV[dt]);
        }
    }
    __syncthreads();  // done reading sxT; region becomes red

#pragma unroll
    for (int dt = 0; dt < 4; ++dt) {
        float* dst = &red[dt][w][lane][0];
        *reinterpret_cast<f32x4*>(dst + 0) = accQ[dt];
        *reinterpret_cast<f32x4*>(dst + 4) = accK[dt];
        *reinterpret_cast<f32x4*>(dst + 8) = accV[dt];
    }
    __syncthreads();

    // wave w reduces + stores the dt=w slice (all waves busy)
    f32x4 q = *reinterpret_cast<const f32x4*>(&red[w][0][lane][0]);
    f32x4 k = *reinterpret_cast<const f32x4*>(&red[w][0][lane][4]);
    f32x4 v = *reinterpret_cast<const f32x4*>(&red[w][0][lane][8]);
#pragma unroll
    for (int src = 1; src < 4; ++src) {
        const float* sp = &red[w][src][lane][0];
        q += *reinterpret_cast<const f32x4*>(sp + 0);
        k += *reinterpret_cast<const f32x4*>(sp + 4);
        v += *reinterpret_cast<const f32x4*>(sp + 8);
    }
    {
        int d = w * 16 + l15;
        float biasq = bq[d], biask = bk[d];
#pragma unroll
        for (int r = 0; r < 4; ++r) {
            int n = n0 + 4 * g + r;
            Q[((size_t)b * NN + n) * DD + d] = f2bf(q[r] + biasq);
            K[((size_t)b * NN + n) * DD + d] = f2bf(k[r] + biask);
        }
#pragma unroll
        for (int r = 0; r < 4; ++r) {
            int dv = w * 16 + 4 * g + r;
            VT[((size_t)b * DD + dv) * NN + n0 + l15] = f2bf(v[r] + bv[dv]);
        }
    }
}

// ---------------- kernel 2: flash attention, KV-split, defer-max ----------------
__global__ __launch_bounds__(256) void attn_kernel(
    const unsigned short* __restrict__ Q, const unsigned short* __restrict__ K,
    const unsigned short* __restrict__ VT,
    unsigned short* __restrict__ PO, float* __restrict__ PML, int KVLEN) {
    const int s = blockIdx.x >> 8;
    const int bq_ = blockIdx.x & 255;
    const int b = bq_ >> 6;
    const int n0 = (bq_ & 63) * 64;
    const int t = threadIdx.x;
    const int lane = t & 63, w = t >> 6;
    const int l15 = lane & 15, g = lane >> 4;

    __shared__ unsigned short sK[64][72];    // [m][d]
    __shared__ unsigned short sVT[64][72];   // [d][m]
    __shared__ unsigned short sP[4][16][76]; // per-wave [n][m]

    const int qrow = n0 + 16 * w + l15;
    bf16x8 qf0 = ld8(&Q[((size_t)b * NN + qrow) * DD + 0 + 8 * g]);
    bf16x8 qf1 = ld8(&Q[((size_t)b * NN + qrow) * DD + 32 + 8 * g]);

    f32x4 oacc[4];
    const f32x4 z = {0.f, 0.f, 0.f, 0.f};
#pragma unroll
    for (int i = 0; i < 4; ++i) oacc[i] = z;
    float m_run[4], l_part[4];
#pragma unroll
    for (int r = 0; r < 4; ++r) { m_run[r] = -1e30f; l_part[r] = 0.f; }

    const int kv_begin = s * KVLEN;
    const int kv_end = kv_begin + KVLEN;
    const int srow = t >> 2, sc16 = (t & 3) * 16;

    // prefetch first tile into regs
    bf16x8 pk0, pk1, pv0, pv1;
    {
        const unsigned short* kp = &K[((size_t)b * NN + kv_begin + srow) * DD + sc16];
        pk0 = ld8(kp); pk1 = ld8(kp + 8);
        const unsigned short* vp = &VT[((size_t)b * DD + srow) * NN + kv_begin + sc16];
        pv0 = ld8(vp); pv1 = ld8(vp + 8);
    }

    for (int m0 = kv_begin; m0 < kv_end; m0 += 64) {
        // write staged regs -> LDS
        *reinterpret_cast<bf16x8*>(&sK[srow][sc16]) = pk0;
        *reinterpret_cast<bf16x8*>(&sK[srow][sc16 + 8]) = pk1;
        *reinterpret_cast<bf16x8*>(&sVT[srow][sc16]) = pv0;
        *reinterpret_cast<bf16x8*>(&sVT[srow][sc16 + 8]) = pv1;
        __syncthreads();

        // issue next-tile global loads early; latency hides under compute
        if (m0 + 64 < kv_end) {
            const unsigned short* kp = &K[((size_t)b * NN + m0 + 64 + srow) * DD + sc16];
            pk0 = ld8(kp); pk1 = ld8(kp + 8);
            const unsigned short* vp = &VT[((size_t)b * DD + srow) * NN + m0 + 64 + sc16];
            pv0 = ld8(vp); pv1 = ld8(vp + 8);
        }

        // S = Q K^T : 16 (n) x 64 (m) per wave
        f32x4 sv[4];
#pragma unroll
        for (int ct = 0; ct < 4; ++ct) sv[ct] = z;
#pragma unroll
        for (int ct = 0; ct < 4; ++ct) {
            bf16x8 kf0 = ld8(&sK[ct * 16 + l15][0 + 8 * g]);
            sv[ct] = MFMA(qf0, kf0, sv[ct]);
            bf16x8 kf1 = ld8(&sK[ct * 16 + l15][32 + 8 * g]);
            sv[ct] = MFMA(qf1, kf1, sv[ct]);
        }

        // defer-max online softmax (T13): no cross-lane reduce in common case
        float ownmax[4];
        bool ok = true;
#pragma unroll
        for (int r = 0; r < 4; ++r) {
            ownmax[r] = fmaxf(fmaxf(sv[0][r], sv[1][r]), fmaxf(sv[2][r], sv[3][r]));
            ok = ok && (ownmax[r] <= m_run[r] + 8.f);
        }
        if (!__all(ok)) {
#pragma unroll
            for (int r = 0; r < 4; ++r) {
                float mx = ownmax[r];
#pragma unroll
                for (int d_ = 8; d_ >= 1; d_ >>= 1) mx = fmaxf(mx, __shfl_xor(mx, d_, 64));
                float mnew = fmaxf(m_run[r], mx);
                float c_ = __expf(m_run[r] - mnew);
                m_run[r] = mnew;
                l_part[r] *= c_;
#pragma unroll
                for (int dt = 0; dt < 4; ++dt) oacc[dt][r] *= c_;
            }
        }
#pragma unroll
        for (int r = 0; r < 4; ++r) {
            float p0 = __expf(sv[0][r] - m_run[r]);
            float p1 = __expf(sv[1][r] - m_run[r]);
            float p2 = __expf(sv[2][r] - m_run[r]);
            float p3 = __expf(sv[3][r] - m_run[r]);
            sv[0][r] = p0; sv[1][r] = p1; sv[2][r] = p2; sv[3][r] = p3;
            l_part[r] += (p0 + p1) + (p2 + p3);
        }

        // P -> LDS (truncating pack; wave-private)
#pragma unroll
        for (int ct = 0; ct < 4; ++ct)
#pragma unroll
            for (int r = 0; r < 4; ++r)
                sP[w][4 * g + r][ct * 16 + l15] = f2bf_trunc(sv[ct][r]);

        // O += P V
#pragma unroll
        for (int kk = 0; kk < 2; ++kk) {
            bf16x8 pf = ld8(&sP[w][l15][kk * 32 + 8 * g]);
#pragma unroll
            for (int dt = 0; dt < 4; ++dt) {
                bf16x8 vf = ld8(&sVT[dt * 16 + l15][kk * 32 + 8 * g]);
                oacc[dt] = MFMA(pf, vf, oacc[dt]);
            }
        }
        __syncthreads();
    }

    // epilogue: reduce deferred l across the 16-lane row group, store partials
#pragma unroll
    for (int r = 0; r < 4; ++r) {
        float lt = l_part[r];
#pragma unroll
        for (int d_ = 8; d_ >= 1; d_ >>= 1) lt += __shfl_xor(lt, d_, 64);
        int n = n0 + 16 * w + 4 * g + r;
        size_t rowidx = (size_t)s * NB * NN + (size_t)b * NN + n;
#pragma unroll
        for (int dt = 0; dt < 4; ++dt)
            PO[rowidx * DD + dt * 16 + l15] = f2bf(oacc[dt][r]);
        if (l15 == 0) {
            PML[rowidx * 2 + 0] = m_run[r];
            PML[rowidx * 2 + 1] = lt;
        }
    }
}

// ---------------- kernel 3: combine + output projection + residual ----------------
__global__ __launch_bounds__(256) void out_fused(
    const unsigned short* __restrict__ Wo, const unsigned short* __restrict__ PO,
    const float* __restrict__ PML, const float* __restrict__ bo,
    const float* __restrict__ gamma, const float* __restrict__ x,
    float* __restrict__ out, int S) {
    const int bid = blockIdx.x;
    const int b = bid >> 8;
    const int rest = bid & 255;
    const int n0 = (rest >> 2) * 64;
    const int c0 = (rest & 3) * 128;
    const int t = threadIdx.x;
    const int lane = t & 63, w = t >> 6;
    const int l15 = lane & 15, g = lane >> 4;

    __shared__ unsigned short sATT[64][72];  // [n][d]

    // phase 1: combine KV-split partials for this n-tile
    {
        const int row = t >> 2;
        const int dq = (t & 3) * 16;
        const size_t base = (size_t)b * NN + n0 + row;
        float m = -1e30f;
        for (int s = 0; s < S; ++s)
            m = fmaxf(m, PML[((size_t)s * NB * NN + base) * 2]);
        float acc[16];
#pragma unroll
        for (int j = 0; j < 16; ++j) acc[j] = 0.f;
        float l = 0.f;
        for (int s = 0; s < S; ++s) {
            size_t rowidx = (size_t)s * NB * NN + base;
            float ms = PML[rowidx * 2 + 0];
            float ls = PML[rowidx * 2 + 1];
            float wgt = __expf(ms - m);
            l += wgt * ls;
            bf16x8 a0 = ld8(&PO[rowidx * DD + dq]);
            bf16x8 a1 = ld8(&PO[rowidx * DD + dq + 8]);
#pragma unroll
            for (int j = 0; j < 8; ++j) {
                acc[j] += wgt * bf2f((unsigned short)a0[j]);
                acc[8 + j] += wgt * bf2f((unsigned short)a1[j]);
            }
        }
        float inv = 1.f / l;
        bf16x8 o0, o1;
#pragma unroll
        for (int j = 0; j < 8; ++j) {
            o0[j] = (short)f2bf(acc[j] * inv);
            o1[j] = (short)f2bf(acc[8 + j] * inv);
        }
        *reinterpret_cast<bf16x8*>(&sATT[row][dq]) = o0;
        *reinterpret_cast<bf16x8*>(&sATT[row][dq + 8]) = o1;
    }
    __syncthreads();

    // phase 2: out[c, n] = gamma*(Wo . att + bo) + x
    const int cw = c0 + w * 32;
    f32x4 acc2[2][4];
    const f32x4 z = {0.f, 0.f, 0.f, 0.f};
#pragma unroll
    for (int i = 0; i < 2; ++i)
#pragma unroll
        for (int j = 0; j < 4; ++j) acc2[i][j] = z;

#pragma unroll
    for (int kk = 0; kk < 2; ++kk) {
        bf16x8 af[2], bfr[4];
#pragma unroll
        for (int ct = 0; ct < 2; ++ct)
            af[ct] = ld8(&Wo[(cw + ct * 16 + l15) * DD + kk * 32 + 8 * g]);
#pragma unroll
        for (int nt = 0; nt < 4; ++nt)
            bfr[nt] = ld8(&sATT[nt * 16 + l15][kk * 32 + 8 * g]);
#pragma unroll
        for (int ct = 0; ct < 2; ++ct)
#pragma unroll
            for (int nt = 0; nt < 4; ++nt) acc2[ct][nt] = MFMA(af[ct], bfr[nt], acc2[ct][nt]);
    }

    float gm = gamma[0];
#pragma unroll
    for (int ct = 0; ct < 2; ++ct) {
        int c = cw + ct * 16 + 4 * g;
#pragma unroll
        for (int r = 0; r < 4; ++r) {
            float bias = bo[c + r];
#pragma unroll
            for (int nt = 0; nt < 4; ++nt) {
                int n = n0 + nt * 16 + l15;
                size_t idx = ((size_t)b * CH + c + r) * NN + n;
                out[idx] = gm * (acc2[ct][nt][r] + bias) + x[idx];
            }
        }
    }
}

extern "C" void kernel_launch(void* const* d_in, const int* in_sizes, int n_in,
                              void* d_out, int out_size, void* d_ws, size_t ws_size,
                              hipStream_t stream) {
    const float* x = (const float*)d_in[0];
    const float* Wq = (const float*)d_in[1];
    const float* bq = (const float*)d_in[2];
    const float* Wk = (const float*)d_in[3];
    const float* bk = (const float*)d_in[4];
    const float* Wv = (const float*)d_in[5];
    const float* bv = (const float*)d_in[6];
    const float* Wo = (const float*)d_in[7];
    const float* bo = (const float*)d_in[8];
    const float* gamma = (const float*)d_in[9];
    float* out = (float*)d_out;

    char* ws = (char*)d_ws;
    unsigned short* Wq_bf = (unsigned short*)(ws + 0);
    unsigned short* Wk_bf = (unsigned short*)(ws + 65536);
    unsigned short* Wv_bf = (unsigned short*)(ws + 131072);
    unsigned short* Wo_bf = (unsigned short*)(ws + 196608);
    unsigned short* Qb = (unsigned short*)(ws + 262144);
    unsigned short* Kb = (unsigned short*)(ws + 262144 + 2097152);
    unsigned short* VTb = (unsigned short*)(ws + 262144 + 2 * 2097152);
    const size_t po_off = 262144 + 3ull * 2097152;

    // KV-split factor (deterministic: depends only on ws_size). S=8 measured
    // worse than S=4 (77.7 vs 69.4 us) -> S=4.
    int S = 4;
    while (S > 1 &&
           ws_size < po_off + (size_t)S * (2097152ull + 131072ull))
        S >>= 1;
    unsigned short* PO = (unsigned short*)(ws + po_off);
    float* PML = (float*)(ws + po_off + (size_t)S * 2097152ull);

    hipLaunchKernelGGL(convert_w, dim3(128), dim3(256), 0, stream,
                       Wq, Wk, Wv, Wo, Wq_bf, Wk_bf, Wv_bf, Wo_bf);
    hipLaunchKernelGGL(qkv_kernel, dim3(1024), dim3(256), 0, stream,
                       x, Wq_bf, Wk_bf, Wv_bf, bq, bk, bv, Qb, Kb, VTb);
    hipLaunchKernelGGL(attn_kernel, dim3(256 * S), dim3(256), 0, stream,
                       Qb, Kb, VTb, PO, PML, NN / S);
    hipLaunchKernelGGL(out_fused, dim3(1024), dim3(256), 0, stream,
                       Wo_bf, PO, PML, bo, gamma, x, out, S);
}